// Round 2
// baseline (69.156 us; speedup 1.0000x reference)
//
#include <hip/hip_runtime.h>
#include <hip/hip_bf16.h>

#define HH 4096
#define WW 4096
#define MAXK (1 << 20)

// ---------------------------------------------------------------------------
// Kernel 1: per-row 3x3 NMS. One block per row, 256 threads x 16 px.
// Writes maxima (int32 0/1), per-thread 16-bit mask (optional), per-row count.
// ---------------------------------------------------------------------------
__global__ __launch_bounds__(256) void k_maxima(
    const float* __restrict__ rel, const float* __restrict__ rep,
    int* __restrict__ mx, unsigned short* __restrict__ masks,
    int* __restrict__ counts)
{
    const int y   = blockIdx.x;
    const int tid = threadIdx.x;
    const int x0  = tid * 16;
    const float NEG = -__builtin_inff();

    float vm[18];       // vertical max over up to 3 rows, window [x0-1, x0+16]
    float center[16];   // rep[y][x0..x0+15]

    {
        const float* row = rep + (size_t)y * WW;
        vm[0]  = (x0 > 0)       ? row[x0 - 1]  : NEG;
        vm[17] = (x0 + 16 < WW) ? row[x0 + 16] : NEG;
#pragma unroll
        for (int j = 0; j < 4; ++j) {
            float4 f = *reinterpret_cast<const float4*>(row + x0 + 4 * j);
            vm[1 + 4 * j] = f.x; vm[2 + 4 * j] = f.y;
            vm[3 + 4 * j] = f.z; vm[4 + 4 * j] = f.w;
        }
#pragma unroll
        for (int i = 0; i < 16; ++i) center[i] = vm[i + 1];
    }
#pragma unroll
    for (int dy = -1; dy <= 1; dy += 2) {
        int yy = y + dy;
        if (yy >= 0 && yy < HH) {
            const float* row = rep + (size_t)yy * WW;
            if (x0 > 0)       vm[0]  = fmaxf(vm[0],  row[x0 - 1]);
            if (x0 + 16 < WW) vm[17] = fmaxf(vm[17], row[x0 + 16]);
#pragma unroll
            for (int j = 0; j < 4; ++j) {
                float4 f = *reinterpret_cast<const float4*>(row + x0 + 4 * j);
                vm[1 + 4 * j] = fmaxf(vm[1 + 4 * j], f.x);
                vm[2 + 4 * j] = fmaxf(vm[2 + 4 * j], f.y);
                vm[3 + 4 * j] = fmaxf(vm[3 + 4 * j], f.z);
                vm[4 + 4 * j] = fmaxf(vm[4 + 4 * j], f.w);
            }
        }
    }
    float rv[16];
    {
        const float* row = rel + (size_t)y * WW;
#pragma unroll
        for (int j = 0; j < 4; ++j) {
            float4 f = *reinterpret_cast<const float4*>(row + x0 + 4 * j);
            rv[4 * j] = f.x; rv[4 * j + 1] = f.y;
            rv[4 * j + 2] = f.z; rv[4 * j + 3] = f.w;
        }
    }

    unsigned int mask = 0;
#pragma unroll
    for (int i = 0; i < 16; ++i) {
        float m3 = fmaxf(fmaxf(vm[i], vm[i + 1]), vm[i + 2]);
        bool is = (center[i] == m3) && (center[i] >= 0.7f) && (rv[i] >= 0.7f);
        mask |= (unsigned int)(is ? 1u : 0u) << i;
    }

    // write maxima as int32 0/1: 16 ints per thread, four 16B stores
    uint4* dst = reinterpret_cast<uint4*>(mx + (size_t)y * WW + x0);
#pragma unroll
    for (int j = 0; j < 4; ++j) {
        dst[j] = make_uint4((mask >> (4 * j))     & 1u,
                            (mask >> (4 * j + 1)) & 1u,
                            (mask >> (4 * j + 2)) & 1u,
                            (mask >> (4 * j + 3)) & 1u);
    }

    if (masks) masks[(size_t)y * 256 + tid] = (unsigned short)mask;

    int cnt = __popc(mask);
#pragma unroll
    for (int off = 32; off; off >>= 1) cnt += __shfl_down(cnt, off, 64);
    __shared__ int wsum[4];
    if ((tid & 63) == 0) wsum[tid >> 6] = cnt;
    __syncthreads();
    if (tid == 0) counts[y] = wsum[0] + wsum[1] + wsum[2] + wsum[3];
}

// ---------------------------------------------------------------------------
// Kernel 2: exclusive scan of 4096 row counts -> row offsets. Single block.
// ---------------------------------------------------------------------------
__global__ __launch_bounds__(256) void k_scan(const int* __restrict__ counts,
                                              int* __restrict__ offsets)
{
    const int tid = threadIdx.x;
    int vals[16];
    int tot = 0;
#pragma unroll
    for (int i = 0; i < 16; ++i) { vals[i] = counts[tid * 16 + i]; tot += vals[i]; }

    const int lane = tid & 63, wid = tid >> 6;
    int inc = tot;
#pragma unroll
    for (int off = 1; off < 64; off <<= 1) {
        int n = __shfl_up(inc, off, 64);
        if (lane >= off) inc += n;
    }
    __shared__ int wsum[4];
    if (lane == 63) wsum[wid] = inc;
    __syncthreads();
    int wbase = 0;
    for (int w = 0; w < wid; ++w) wbase += wsum[w];

    int run = wbase + inc - tot;
#pragma unroll
    for (int i = 0; i < 16; ++i) { offsets[tid * 16 + i] = run; run += vals[i]; }
}

// ---------------------------------------------------------------------------
// Kernel 3: fill coords region (2*MAXK int32) with -1.
// ---------------------------------------------------------------------------
__global__ __launch_bounds__(256) void k_fill(uint4* __restrict__ p)
{
    const int i = blockIdx.x * 256 + threadIdx.x;
    p[i] = make_uint4(0xFFFFFFFFu, 0xFFFFFFFFu, 0xFFFFFFFFu, 0xFFFFFFFFu);
}

// ---------------------------------------------------------------------------
// Kernel 4a: ordered compaction from per-thread masks stored in ws.
// ---------------------------------------------------------------------------
__global__ __launch_bounds__(256) void k_emit_ws(
    const unsigned short* __restrict__ masks, const int* __restrict__ offsets,
    int* __restrict__ oy, int* __restrict__ ox)
{
    const int y   = blockIdx.x;
    const int tid = threadIdx.x;
    unsigned int mask = masks[(size_t)y * 256 + tid];

    int cnt = __popc(mask);
    const int lane = tid & 63, wid = tid >> 6;
    int inc = cnt;
#pragma unroll
    for (int off = 1; off < 64; off <<= 1) {
        int n = __shfl_up(inc, off, 64);
        if (lane >= off) inc += n;
    }
    __shared__ int wsum[4];
    if (lane == 63) wsum[wid] = inc;
    __syncthreads();
    int wbase = 0;
    for (int w = 0; w < wid; ++w) wbase += wsum[w];

    int pos = offsets[y] + wbase + inc - cnt;
    const int x0 = tid * 16;
    while (mask) {
        int b = __ffs(mask) - 1;
        mask &= mask - 1;
        if (pos < MAXK) { oy[pos] = y; ox[pos] = x0 + b; }
        ++pos;
    }
}

// ---------------------------------------------------------------------------
// Kernel 4b: fallback — rebuild mask from the int32 maxima array.
// ---------------------------------------------------------------------------
__global__ __launch_bounds__(256) void k_emit_mx(
    const int* __restrict__ mx, const int* __restrict__ offsets,
    int* __restrict__ oy, int* __restrict__ ox)
{
    const int y   = blockIdx.x;
    const int tid = threadIdx.x;
    const int x0  = tid * 16;

    unsigned int mask = 0;
    const uint4* p = reinterpret_cast<const uint4*>(mx + (size_t)y * WW + x0);
#pragma unroll
    for (int j = 0; j < 4; ++j) {
        uint4 f = p[j];
        if (f.x) mask |= 1u << (4 * j);
        if (f.y) mask |= 1u << (4 * j + 1);
        if (f.z) mask |= 1u << (4 * j + 2);
        if (f.w) mask |= 1u << (4 * j + 3);
    }

    int cnt = __popc(mask);
    const int lane = tid & 63, wid = tid >> 6;
    int inc = cnt;
#pragma unroll
    for (int off = 1; off < 64; off <<= 1) {
        int n = __shfl_up(inc, off, 64);
        if (lane >= off) inc += n;
    }
    __shared__ int wsum[4];
    if (lane == 63) wsum[wid] = inc;
    __syncthreads();
    int wbase = 0;
    for (int w = 0; w < wid; ++w) wbase += wsum[w];

    int pos = offsets[y] + wbase + inc - cnt;
    while (mask) {
        int b = __ffs(mask) - 1;
        mask &= mask - 1;
        if (pos < MAXK) { oy[pos] = y; ox[pos] = x0 + b; }
        ++pos;
    }
}

// ---------------------------------------------------------------------------
extern "C" void kernel_launch(void* const* d_in, const int* in_sizes, int n_in,
                              void* d_out, int out_size, void* d_ws, size_t ws_size,
                              hipStream_t stream)
{
    const float* rel = (const float*)d_in[0];   // reliability
    const float* rep = (const float*)d_in[1];   // repeatability

    int* out = (int*)d_out;
    int* mx  = out;                       // 4096*4096 maxima (int32 0/1)
    int* oy  = out + (size_t)HH * WW;     // 2^20 y coords
    int* ox  = oy + MAXK;                 // 2^20 x coords

    int* counts  = (int*)d_ws;            // 4096 ints
    int* offsets = counts + HH;           // 4096 ints
    unsigned short* masks = (unsigned short*)(offsets + HH);  // 4096*256 ushort

    const size_t need_ws = (size_t)2 * HH * sizeof(int)
                         + (size_t)HH * 256 * sizeof(unsigned short);
    const bool use_masks = ws_size >= need_ws;

    k_maxima<<<HH, 256, 0, stream>>>(rel, rep, mx, use_masks ? masks : nullptr,
                                     counts);
    k_scan<<<1, 256, 0, stream>>>(counts, offsets);
    k_fill<<<(2 * MAXK) * 4 / 16 / 256, 256, 0, stream>>>((uint4*)oy);
    if (use_masks)
        k_emit_ws<<<HH, 256, 0, stream>>>(masks, offsets, oy, ox);
    else
        k_emit_mx<<<HH, 256, 0, stream>>>(mx, offsets, oy, ox);
}

// Round 3
// 68.554 us; speedup vs baseline: 1.0088x; 1.0088x over previous
//
#include <hip/hip_runtime.h>
#include <hip/hip_bf16.h>

#define HH 4096
#define WW 4096
#define MAXK (1 << 20)   // == HH * 256

// ---------------------------------------------------------------------------
// Kernel 1: per-row 3x3 NMS. One block per row, 256 threads x 16 px.
// All loads unconditional with clamp-to-edge (identical to -inf SAME padding
// for a max filter). Loads batched up front for MLP.
// ---------------------------------------------------------------------------
__global__ __launch_bounds__(256) void k_maxima(
    const float* __restrict__ rel, const float* __restrict__ rep,
    int* __restrict__ mx, unsigned short* __restrict__ masks,
    int* __restrict__ counts)
{
    const int y   = blockIdx.x;
    const int tid = threadIdx.x;
    const int x0  = tid * 16;

    const float* rowC = rep + (size_t)y * WW;
    const float* rowU = rep + (size_t)(y > 0      ? y - 1 : 0     ) * WW;
    const float* rowD = rep + (size_t)(y < HH - 1 ? y + 1 : HH - 1) * WW;
    const float* rowR = rel + (size_t)y * WW;

    const int xl = (x0 > 0)       ? x0 - 1  : 0;
    const int xr = (x0 + 16 < WW) ? x0 + 16 : WW - 1;

    // ---- issue ALL loads up front (22 independent VMEM ops) ----
    float4 u4[4], c4[4], d4[4], r4[4];
#pragma unroll
    for (int j = 0; j < 4; ++j) u4[j] = *reinterpret_cast<const float4*>(rowU + x0 + 4 * j);
#pragma unroll
    for (int j = 0; j < 4; ++j) c4[j] = *reinterpret_cast<const float4*>(rowC + x0 + 4 * j);
#pragma unroll
    for (int j = 0; j < 4; ++j) d4[j] = *reinterpret_cast<const float4*>(rowD + x0 + 4 * j);
#pragma unroll
    for (int j = 0; j < 4; ++j) r4[j] = *reinterpret_cast<const float4*>(rowR + x0 + 4 * j);
    const float uL = rowU[xl], cL = rowC[xl], dL = rowD[xl];
    const float uR = rowU[xr], cR = rowC[xr], dR = rowD[xr];

    // ---- vertical 3-max into an 18-wide window ----
    float c[16], vm[18];
#pragma unroll
    for (int j = 0; j < 4; ++j) {
        const float u[4] = {u4[j].x, u4[j].y, u4[j].z, u4[j].w};
        const float cc[4] = {c4[j].x, c4[j].y, c4[j].z, c4[j].w};
        const float d[4] = {d4[j].x, d4[j].y, d4[j].z, d4[j].w};
#pragma unroll
        for (int k = 0; k < 4; ++k) {
            c[4 * j + k]      = cc[k];
            vm[1 + 4 * j + k] = fmaxf(fmaxf(u[k], cc[k]), d[k]);
        }
    }
    vm[0]  = fmaxf(fmaxf(uL, cL), dL);
    vm[17] = fmaxf(fmaxf(uR, cR), dR);

    const float rv[16] = {r4[0].x, r4[0].y, r4[0].z, r4[0].w,
                          r4[1].x, r4[1].y, r4[1].z, r4[1].w,
                          r4[2].x, r4[2].y, r4[2].z, r4[2].w,
                          r4[3].x, r4[3].y, r4[3].z, r4[3].w};

    unsigned int mask = 0;
#pragma unroll
    for (int i = 0; i < 16; ++i) {
        float m3 = fmaxf(fmaxf(vm[i], vm[i + 1]), vm[i + 2]);
        bool is = (c[i] == m3) && (c[i] >= 0.7f) && (rv[i] >= 0.7f);
        mask |= (unsigned int)(is ? 1u : 0u) << i;
    }

    // ---- maxima as int32 0/1: four 16B stores ----
    uint4* dst = reinterpret_cast<uint4*>(mx + (size_t)y * WW + x0);
#pragma unroll
    for (int j = 0; j < 4; ++j) {
        dst[j] = make_uint4((mask >> (4 * j))     & 1u,
                            (mask >> (4 * j + 1)) & 1u,
                            (mask >> (4 * j + 2)) & 1u,
                            (mask >> (4 * j + 3)) & 1u);
    }

    if (masks) masks[(size_t)y * 256 + tid] = (unsigned short)mask;

    int cnt = __popc(mask);
#pragma unroll
    for (int off = 32; off; off >>= 1) cnt += __shfl_down(cnt, off, 64);
    __shared__ int wsum[4];
    if ((tid & 63) == 0) wsum[tid >> 6] = cnt;
    __syncthreads();
    if (tid == 0) counts[y] = wsum[0] + wsum[1] + wsum[2] + wsum[3];
}

// ---------------------------------------------------------------------------
// Kernel 2: exclusive scan of 4096 row counts -> offsets[0..HH-1], total in
// offsets[HH]. Single block.
// ---------------------------------------------------------------------------
__global__ __launch_bounds__(256) void k_scan(const int* __restrict__ counts,
                                              int* __restrict__ offsets)
{
    const int tid = threadIdx.x;
    int vals[16];
    int tot = 0;
#pragma unroll
    for (int i = 0; i < 16; ++i) { vals[i] = counts[tid * 16 + i]; tot += vals[i]; }

    const int lane = tid & 63, wid = tid >> 6;
    int inc = tot;
#pragma unroll
    for (int off = 1; off < 64; off <<= 1) {
        int n = __shfl_up(inc, off, 64);
        if (lane >= off) inc += n;
    }
    __shared__ int wsum[4];
    if (lane == 63) wsum[wid] = inc;
    __syncthreads();
    int wbase = 0;
    for (int w = 0; w < wid; ++w) wbase += wsum[w];

    int run = wbase + inc - tot;
#pragma unroll
    for (int i = 0; i < 16; ++i) { offsets[tid * 16 + i] = run; run += vals[i]; }
    if (tid == 255) offsets[HH] = run;   // total keypoint count
}

// ---------------------------------------------------------------------------
// Kernel 4a: ordered compaction from per-thread masks in ws, with the -1 tail
// fill fused in (MAXK == HH*256, so block y owns slice [y*256, y*256+256)).
// ---------------------------------------------------------------------------
__global__ __launch_bounds__(256) void k_emit_ws(
    const unsigned short* __restrict__ masks, const int* __restrict__ offsets,
    int* __restrict__ oy, int* __restrict__ ox)
{
    const int y   = blockIdx.x;
    const int tid = threadIdx.x;

    // fused tail fill
    const int total = offsets[HH];
    const int slot  = y * 256 + tid;
    if (slot >= total) { oy[slot] = -1; ox[slot] = -1; }

    unsigned int mask = masks[(size_t)y * 256 + tid];

    int cnt = __popc(mask);
    const int lane = tid & 63, wid = tid >> 6;
    int inc = cnt;
#pragma unroll
    for (int off = 1; off < 64; off <<= 1) {
        int n = __shfl_up(inc, off, 64);
        if (lane >= off) inc += n;
    }
    __shared__ int wsum[4];
    if (lane == 63) wsum[wid] = inc;
    __syncthreads();
    int wbase = 0;
    for (int w = 0; w < wid; ++w) wbase += wsum[w];

    int pos = offsets[y] + wbase + inc - cnt;
    const int x0 = tid * 16;
    while (mask) {
        int b = __ffs(mask) - 1;
        mask &= mask - 1;
        if (pos < MAXK) { oy[pos] = y; ox[pos] = x0 + b; }
        ++pos;
    }
}

// ---------------------------------------------------------------------------
// Kernel 4b: fallback — rebuild mask from the int32 maxima array.
// ---------------------------------------------------------------------------
__global__ __launch_bounds__(256) void k_emit_mx(
    const int* __restrict__ mx, const int* __restrict__ offsets,
    int* __restrict__ oy, int* __restrict__ ox)
{
    const int y   = blockIdx.x;
    const int tid = threadIdx.x;
    const int x0  = tid * 16;

    const int total = offsets[HH];
    const int slot  = y * 256 + tid;
    if (slot >= total) { oy[slot] = -1; ox[slot] = -1; }

    unsigned int mask = 0;
    const uint4* p = reinterpret_cast<const uint4*>(mx + (size_t)y * WW + x0);
#pragma unroll
    for (int j = 0; j < 4; ++j) {
        uint4 f = p[j];
        if (f.x) mask |= 1u << (4 * j);
        if (f.y) mask |= 1u << (4 * j + 1);
        if (f.z) mask |= 1u << (4 * j + 2);
        if (f.w) mask |= 1u << (4 * j + 3);
    }

    int cnt = __popc(mask);
    const int lane = tid & 63, wid = tid >> 6;
    int inc = cnt;
#pragma unroll
    for (int off = 1; off < 64; off <<= 1) {
        int n = __shfl_up(inc, off, 64);
        if (lane >= off) inc += n;
    }
    __shared__ int wsum[4];
    if (lane == 63) wsum[wid] = inc;
    __syncthreads();
    int wbase = 0;
    for (int w = 0; w < wid; ++w) wbase += wsum[w];

    int pos = offsets[y] + wbase + inc - cnt;
    while (mask) {
        int b = __ffs(mask) - 1;
        mask &= mask - 1;
        if (pos < MAXK) { oy[pos] = y; ox[pos] = x0 + b; }
        ++pos;
    }
}

// ---------------------------------------------------------------------------
extern "C" void kernel_launch(void* const* d_in, const int* in_sizes, int n_in,
                              void* d_out, int out_size, void* d_ws, size_t ws_size,
                              hipStream_t stream)
{
    const float* rel = (const float*)d_in[0];   // reliability
    const float* rep = (const float*)d_in[1];   // repeatability

    int* out = (int*)d_out;
    int* mx  = out;                       // 4096*4096 maxima (int32 0/1)
    int* oy  = out + (size_t)HH * WW;     // 2^20 y coords
    int* ox  = oy + MAXK;                 // 2^20 x coords

    int* counts  = (int*)d_ws;                 // HH ints
    int* offsets = counts + HH;                // HH+1 ints
    unsigned short* masks = (unsigned short*)(offsets + HH + 1);  // HH*256

    const size_t need_ws = (size_t)(2 * HH + 1) * sizeof(int)
                         + (size_t)HH * 256 * sizeof(unsigned short);
    const bool use_masks = ws_size >= need_ws;

    k_maxima<<<HH, 256, 0, stream>>>(rel, rep, mx, use_masks ? masks : nullptr,
                                     counts);
    k_scan<<<1, 256, 0, stream>>>(counts, offsets);
    if (use_masks)
        k_emit_ws<<<HH, 256, 0, stream>>>(masks, offsets, oy, ox);
    else
        k_emit_mx<<<HH, 256, 0, stream>>>(mx, offsets, oy, ox);
}

// Round 4
// 61.088 us; speedup vs baseline: 1.1321x; 1.1222x over previous
//
#include <hip/hip_runtime.h>

#define HH 4096
#define WW 4096
#define MAXK (1 << 20)      // == NBLK * 64
#define NSEG 4              // segments per row
#define SEGW 1024           // pixels per segment
#define NBLK (HH * NSEG)    // 16384 blocks

// ---------------------------------------------------------------------------
// Kernel 1: 3x3 NMS, one block per 1024-px row segment, 256 thr x 4 px.
// ALL global accesses lane-contiguous (float4/int4 per lane). Horizontal
// window via LDS vertical-max array; clamp-to-edge == -inf SAME pad for max.
// ---------------------------------------------------------------------------
__global__ __launch_bounds__(256) void k_maxima(
    const float* __restrict__ rel, const float* __restrict__ rep,
    int* __restrict__ mx, unsigned char* __restrict__ masks,
    int* __restrict__ counts)
{
    const int bid = blockIdx.x;
    const int y   = bid >> 2;
    const int seg = bid & 3;
    const int tid = threadIdx.x;
    const int x0  = seg * SEGW + tid * 4;

    const float* rowC = rep + (size_t)y * WW;
    const float* rowU = rep + (size_t)(y > 0      ? y - 1 : 0     ) * WW;
    const float* rowD = rep + (size_t)(y < HH - 1 ? y + 1 : HH - 1) * WW;

    const float4 u4 = *reinterpret_cast<const float4*>(rowU + x0);
    const float4 c4 = *reinterpret_cast<const float4*>(rowC + x0);
    const float4 d4 = *reinterpret_cast<const float4*>(rowD + x0);
    const float4 r4 = *reinterpret_cast<const float4*>(rel + (size_t)y * WW + x0);

    // vertical 3-max
    const float vm0 = fmaxf(fmaxf(u4.x, c4.x), d4.x);
    const float vm1 = fmaxf(fmaxf(u4.y, c4.y), d4.y);
    const float vm2 = fmaxf(fmaxf(u4.z, c4.z), d4.z);
    const float vm3 = fmaxf(fmaxf(u4.w, c4.w), d4.w);

    __shared__ float vmsh[SEGW + 2];   // [0..1023] main, [1024]=haloL, [1025]=haloR
    *reinterpret_cast<float4*>(vmsh + tid * 4) = make_float4(vm0, vm1, vm2, vm3);

    if (tid == 0) {        // halo column left of segment (clamped)
        const int xl = (x0 > 0) ? x0 - 1 : 0;
        vmsh[SEGW] = fmaxf(fmaxf(rowU[xl], rowC[xl]), rowD[xl]);
    }
    if (tid == 255) {      // halo column right of segment (clamped)
        const int xr = (x0 + 4 < WW) ? x0 + 4 : WW - 1;
        vmsh[SEGW + 1] = fmaxf(fmaxf(rowU[xr], rowC[xr]), rowD[xr]);
    }
    __syncthreads();

    const float vmL = vmsh[tid       ? tid * 4 - 1 : SEGW    ];
    const float vmR = vmsh[tid < 255 ? tid * 4 + 4 : SEGW + 1];

    const float m30 = fmaxf(fmaxf(vmL, vm0), vm1);
    const float m31 = fmaxf(fmaxf(vm0, vm1), vm2);
    const float m32 = fmaxf(fmaxf(vm1, vm2), vm3);
    const float m33 = fmaxf(fmaxf(vm2, vm3), vmR);

    unsigned int mask = 0;
    if (c4.x == m30 && c4.x >= 0.7f && r4.x >= 0.7f) mask |= 1u;
    if (c4.y == m31 && c4.y >= 0.7f && r4.y >= 0.7f) mask |= 2u;
    if (c4.z == m32 && c4.z >= 0.7f && r4.z >= 0.7f) mask |= 4u;
    if (c4.w == m33 && c4.w >= 0.7f && r4.w >= 0.7f) mask |= 8u;

    // maxima as int32 0/1: one lane-contiguous 16B store
    *reinterpret_cast<int4*>(mx + (size_t)y * WW + x0) =
        make_int4(mask & 1u, (mask >> 1) & 1u, (mask >> 2) & 1u, (mask >> 3) & 1u);

    if (masks) masks[(size_t)bid * 256 + tid] = (unsigned char)mask;

    int cnt = __popc(mask);
#pragma unroll
    for (int off = 32; off; off >>= 1) cnt += __shfl_down(cnt, off, 64);
    __shared__ int wsum[4];
    if ((tid & 63) == 0) wsum[tid >> 6] = cnt;
    __syncthreads();
    if (tid == 0) counts[bid] = wsum[0] + wsum[1] + wsum[2] + wsum[3];
}

// ---------------------------------------------------------------------------
// Kernel 2: exclusive scan of 16384 segment counts. Single block, 64/thread.
// offsets[NBLK] = total.
// ---------------------------------------------------------------------------
__global__ __launch_bounds__(256) void k_scan(const int* __restrict__ counts,
                                              int* __restrict__ offsets)
{
    const int tid = threadIdx.x;
    int v[64];
    int tot = 0;
    const int4* src = reinterpret_cast<const int4*>(counts + tid * 64);
#pragma unroll
    for (int i = 0; i < 16; ++i) {
        int4 a = src[i];
        v[4 * i] = a.x; v[4 * i + 1] = a.y; v[4 * i + 2] = a.z; v[4 * i + 3] = a.w;
        tot += a.x + a.y + a.z + a.w;
    }

    const int lane = tid & 63, wid = tid >> 6;
    int inc = tot;
#pragma unroll
    for (int off = 1; off < 64; off <<= 1) {
        int n = __shfl_up(inc, off, 64);
        if (lane >= off) inc += n;
    }
    __shared__ int wsum[4];
    if (lane == 63) wsum[wid] = inc;
    __syncthreads();
    int wbase = 0;
    for (int w = 0; w < wid; ++w) wbase += wsum[w];

    int run = wbase + inc - tot;       // exclusive prefix for this thread
    int4* dst = reinterpret_cast<int4*>(offsets + tid * 64);
#pragma unroll
    for (int i = 0; i < 16; ++i) {
        int4 o;
        o.x = run; run += v[4 * i];
        o.y = run; run += v[4 * i + 1];
        o.z = run; run += v[4 * i + 2];
        o.w = run; run += v[4 * i + 3];
        dst[i] = o;
    }
    if (tid == 255) offsets[NBLK] = run;   // total keypoint count
}

// ---------------------------------------------------------------------------
// Kernel 3a: ordered compaction from byte masks, fused -1 tail fill
// (block owns coord slots [bid*64, bid*64+64)).
// ---------------------------------------------------------------------------
__global__ __launch_bounds__(256) void k_emit_ws(
    const unsigned char* __restrict__ masks, const int* __restrict__ offsets,
    int* __restrict__ oy, int* __restrict__ ox)
{
    const int bid = blockIdx.x;
    const int tid = threadIdx.x;

    const int total = offsets[NBLK];
    if (tid < 64) {
        const int slot = bid * 64 + tid;
        if (slot >= total) { oy[slot] = -1; ox[slot] = -1; }
    }

    unsigned int mask = masks[(size_t)bid * 256 + tid];

    int cnt = __popc(mask);
    const int lane = tid & 63, wid = tid >> 6;
    int inc = cnt;
#pragma unroll
    for (int off = 1; off < 64; off <<= 1) {
        int n = __shfl_up(inc, off, 64);
        if (lane >= off) inc += n;
    }
    __shared__ int wsum[4];
    if (lane == 63) wsum[wid] = inc;
    __syncthreads();
    int wbase = 0;
    for (int w = 0; w < wid; ++w) wbase += wsum[w];

    int pos = offsets[bid] + wbase + inc - cnt;
    const int y  = bid >> 2;
    const int xb = (bid & 3) * SEGW + tid * 4;
    while (mask) {
        int b = __ffs(mask) - 1;
        mask &= mask - 1;
        if (pos < MAXK) { oy[pos] = y; ox[pos] = xb + b; }
        ++pos;
    }
}

// ---------------------------------------------------------------------------
// Kernel 3b: fallback — rebuild mask from the int32 maxima array.
// ---------------------------------------------------------------------------
__global__ __launch_bounds__(256) void k_emit_mx(
    const int* __restrict__ mx, const int* __restrict__ offsets,
    int* __restrict__ oy, int* __restrict__ ox)
{
    const int bid = blockIdx.x;
    const int tid = threadIdx.x;
    const int y   = bid >> 2;
    const int xb  = (bid & 3) * SEGW + tid * 4;

    const int total = offsets[NBLK];
    if (tid < 64) {
        const int slot = bid * 64 + tid;
        if (slot >= total) { oy[slot] = -1; ox[slot] = -1; }
    }

    const int4 f = *reinterpret_cast<const int4*>(mx + (size_t)y * WW + xb);
    unsigned int mask = 0;
    if (f.x) mask |= 1u;
    if (f.y) mask |= 2u;
    if (f.z) mask |= 4u;
    if (f.w) mask |= 8u;

    int cnt = __popc(mask);
    const int lane = tid & 63, wid = tid >> 6;
    int inc = cnt;
#pragma unroll
    for (int off = 1; off < 64; off <<= 1) {
        int n = __shfl_up(inc, off, 64);
        if (lane >= off) inc += n;
    }
    __shared__ int wsum[4];
    if (lane == 63) wsum[wid] = inc;
    __syncthreads();
    int wbase = 0;
    for (int w = 0; w < wid; ++w) wbase += wsum[w];

    int pos = offsets[bid] + wbase + inc - cnt;
    while (mask) {
        int b = __ffs(mask) - 1;
        mask &= mask - 1;
        if (pos < MAXK) { oy[pos] = y; ox[pos] = xb + b; }
        ++pos;
    }
}

// ---------------------------------------------------------------------------
extern "C" void kernel_launch(void* const* d_in, const int* in_sizes, int n_in,
                              void* d_out, int out_size, void* d_ws, size_t ws_size,
                              hipStream_t stream)
{
    const float* rel = (const float*)d_in[0];   // reliability
    const float* rep = (const float*)d_in[1];   // repeatability

    int* out = (int*)d_out;
    int* mx  = out;                       // 4096*4096 maxima (int32 0/1)
    int* oy  = out + (size_t)HH * WW;     // 2^20 y coords
    int* ox  = oy + MAXK;                 // 2^20 x coords

    int* counts  = (int*)d_ws;                       // NBLK ints
    int* offsets = counts + NBLK;                    // NBLK+1 ints (+pad)
    unsigned char* masks = (unsigned char*)(offsets + NBLK + 4);  // NBLK*256 B

    const size_t need_ws = (size_t)(2 * NBLK + 4) * sizeof(int)
                         + (size_t)NBLK * 256;
    const bool use_masks = ws_size >= need_ws;

    k_maxima<<<NBLK, 256, 0, stream>>>(rel, rep, mx, use_masks ? masks : nullptr,
                                       counts);
    k_scan<<<1, 256, 0, stream>>>(counts, offsets);
    if (use_masks)
        k_emit_ws<<<NBLK, 256, 0, stream>>>(masks, offsets, oy, ox);
    else
        k_emit_mx<<<NBLK, 256, 0, stream>>>(mx, offsets, oy, ox);
}